// Round 1
// 1204.700 us; speedup vs baseline: 1.1457x; 1.1457x over previous
//
#include <hip/hip_runtime.h>

#define NFFT 2048
#define LDK 40  // padded LDS row length in bf16 units (32 data + 8 pad)
#define FFT_PAD(p) ((p) + ((p) >> 5))

typedef __attribute__((ext_vector_type(8))) short bf16x8;
typedef __attribute__((ext_vector_type(4))) float f32x4;

__device__ __forceinline__ unsigned short f2bf_rne(float x) {
  unsigned u = __float_as_uint(x);
  return (unsigned short)((u + 0x7fffu + ((u >> 16) & 1u)) >> 16);
}
__device__ __forceinline__ float bf2f(unsigned short h) {
  return __uint_as_float(((unsigned)h) << 16);
}

// ---------------------------------------------------------------------------
// Weight split+transpose: W[k][n] fp32 -> WThi[n][k], WTlo[n][k] bf16.
// ---------------------------------------------------------------------------
__global__ __launch_bounds__(256) void wsplit_kernel(
    const float* __restrict__ W0, const float* __restrict__ W1,
    const float* __restrict__ W2, const float* __restrict__ W3,
    unsigned short* __restrict__ out) {
  __shared__ float tile[32][33];
  const float* W = (blockIdx.z == 0) ? W0
                   : (blockIdx.z == 1) ? W1
                   : (blockIdx.z == 2) ? W2 : W3;
  unsigned short* hi = out + (size_t)blockIdx.z * 524288;
  unsigned short* lo = hi + 262144;
  const int k0 = blockIdx.x * 32, n0 = blockIdx.y * 32;
  const int c = threadIdx.x & 31, r = threadIdx.x >> 5;
#pragma unroll
  for (int p = 0; p < 4; p++)
    tile[r + 8 * p][c] = W[(size_t)(k0 + r + 8 * p) * 512 + n0 + c];
  __syncthreads();
#pragma unroll
  for (int p = 0; p < 4; p++) {
    int nn = r + 8 * p;
    float x = tile[c][nn];
    unsigned u = __float_as_uint(x);
    unsigned short h = (unsigned short)(u >> 16);
    float hf = __uint_as_float(u & 0xffff0000u);
    unsigned short l = f2bf_rne(x - hf);
    hi[(size_t)(n0 + nn) * 512 + k0 + c] = h;
    lo[(size_t)(n0 + nn) * 512 + k0 + c] = l;
  }
}

// ---------------------------------------------------------------------------
// Split-bf16 projection GEMM (3-product, ~fp32 accuracy), TRANSPOSED output.
// ---------------------------------------------------------------------------
__global__ __launch_bounds__(256) void proj_gemm_split(
    const float* __restrict__ X, const unsigned short* __restrict__ WThi,
    const unsigned short* __restrict__ WTlo, const float* __restrict__ bias,
    float* __restrict__ YT) {
  __shared__ __align__(16) unsigned short Wh[128 * LDK];
  __shared__ __align__(16) unsigned short Wl[128 * LDK];
  __shared__ __align__(16) unsigned short Xh[128 * LDK];
  __shared__ __align__(16) unsigned short Xl[128 * LDK];
  const int tid = threadIdx.x;
  const int n0 = blockIdx.x * 128;
  const int b = blockIdx.y >> 4;
  const int t0 = (blockIdx.y & 15) * 128;
  const int w = tid >> 6, l = tid & 63;
  const int wn = (w & 1) * 64;
  const int wt = (w >> 1) * 64;
  const int fr = l & 15;
  const int fk = (l >> 4) * 8;

  f32x4 acc[4][4];
#pragma unroll
  for (int i = 0; i < 4; i++)
#pragma unroll
    for (int j = 0; j < 4; j++) acc[i][j] = (f32x4)0.f;

  const int srow = tid >> 1, scol = (tid & 1) * 16;
  const float* Xg = X + ((size_t)(b * 2048 + t0 + srow)) * 512 + scol;
  const unsigned short* Whg = WThi + ((size_t)(n0 + srow)) * 512 + scol;
  const unsigned short* Wlg = WTlo + ((size_t)(n0 + srow)) * 512 + scol;
  unsigned short* XhL = &Xh[srow * LDK + scol];
  unsigned short* XlL = &Xl[srow * LDK + scol];
  unsigned short* WhL = &Wh[srow * LDK + scol];
  unsigned short* WlL = &Wl[srow * LDK + scol];

  for (int k0 = 0; k0 < 512; k0 += 32) {
    float xv[16];
    *(float4*)&xv[0] = *(const float4*)&Xg[k0];
    *(float4*)&xv[4] = *(const float4*)&Xg[k0 + 4];
    *(float4*)&xv[8] = *(const float4*)&Xg[k0 + 8];
    *(float4*)&xv[12] = *(const float4*)&Xg[k0 + 12];
    uint4 wh0 = *(const uint4*)&Whg[k0];
    uint4 wh1 = *(const uint4*)&Whg[k0 + 8];
    uint4 wl0 = *(const uint4*)&Wlg[k0];
    uint4 wl1 = *(const uint4*)&Wlg[k0 + 8];
    union { unsigned short us[16]; uint4 q[2]; } hb, lb;
#pragma unroll
    for (int i = 0; i < 16; i++) {
      unsigned u = __float_as_uint(xv[i]);
      hb.us[i] = (unsigned short)(u >> 16);
      float hf = __uint_as_float(u & 0xffff0000u);
      lb.us[i] = f2bf_rne(xv[i] - hf);
    }
    __syncthreads();
    *(uint4*)&XhL[0] = hb.q[0];
    *(uint4*)&XhL[8] = hb.q[1];
    *(uint4*)&XlL[0] = lb.q[0];
    *(uint4*)&XlL[8] = lb.q[1];
    *(uint4*)&WhL[0] = wh0;
    *(uint4*)&WhL[8] = wh1;
    *(uint4*)&WlL[0] = wl0;
    *(uint4*)&WlL[8] = wl1;
    __syncthreads();
    bf16x8 ah[4], al[4], bh[4], bl[4];
#pragma unroll
    for (int i = 0; i < 4; i++) {
      ah[i] = *(const bf16x8*)&Wh[(wn + 16 * i + fr) * LDK + fk];
      al[i] = *(const bf16x8*)&Wl[(wn + 16 * i + fr) * LDK + fk];
      bh[i] = *(const bf16x8*)&Xh[(wt + 16 * i + fr) * LDK + fk];
      bl[i] = *(const bf16x8*)&Xl[(wt + 16 * i + fr) * LDK + fk];
    }
#pragma unroll
    for (int i = 0; i < 4; i++)
#pragma unroll
      for (int j = 0; j < 4; j++) {
        acc[i][j] = __builtin_amdgcn_mfma_f32_16x16x32_bf16(ah[i], bh[j],
                                                            acc[i][j], 0, 0, 0);
        acc[i][j] = __builtin_amdgcn_mfma_f32_16x16x32_bf16(al[i], bh[j],
                                                            acc[i][j], 0, 0, 0);
        acc[i][j] = __builtin_amdgcn_mfma_f32_16x16x32_bf16(ah[i], bl[j],
                                                            acc[i][j], 0, 0, 0);
      }
  }
  const size_t obase = (size_t)b * 512 * 2048;
#pragma unroll
  for (int i = 0; i < 4; i++) {
#pragma unroll
    for (int r = 0; r < 4; r++) {
      int n = n0 + wn + 16 * i + (l >> 4) * 4 + r;
      float bsc = bias[n];
      size_t row = obase + (size_t)n * 2048 + t0 + wt + (l & 15);
#pragma unroll
      for (int j = 0; j < 4; j++) YT[row + 16 * j] = acc[i][j][r] + bsc;
    }
  }
}

// ---------------------------------------------------------------------------
// Plain-bf16 GEMM for v projection.
// ---------------------------------------------------------------------------
__global__ __launch_bounds__(256) void gemm_bf16_vproj(
    const float* __restrict__ X, const unsigned short* __restrict__ WThi,
    const float* __restrict__ bias, unsigned short* __restrict__ Vbf) {
  __shared__ __align__(16) unsigned short Ws[128 * LDK];
  __shared__ __align__(16) unsigned short Xs[128 * LDK];
  const int tid = threadIdx.x;
  const int n0 = blockIdx.x * 128;
  const int b = blockIdx.y >> 4;
  const int t0 = (blockIdx.y & 15) * 128;
  const int w = tid >> 6, l = tid & 63;
  const int wr = (w & 1) * 64;
  const int wc = (w >> 1) * 64;
  const int fr = l & 15, fk = (l >> 4) * 8;

  f32x4 acc[4][4];
#pragma unroll
  for (int i = 0; i < 4; i++)
#pragma unroll
    for (int j = 0; j < 4; j++) acc[i][j] = (f32x4)0.f;

  const int srow = tid >> 1, scol = (tid & 1) * 16;
  const float* Xg = X + ((size_t)(b * 2048 + t0 + srow)) * 512 + scol;
  const unsigned short* Wg = WThi + ((size_t)(n0 + srow)) * 512 + scol;
  unsigned short* XsL = &Xs[srow * LDK + scol];
  unsigned short* WsL = &Ws[srow * LDK + scol];

  for (int k0 = 0; k0 < 512; k0 += 32) {
    float xv[16];
    *(float4*)&xv[0] = *(const float4*)&Xg[k0];
    *(float4*)&xv[4] = *(const float4*)&Xg[k0 + 4];
    *(float4*)&xv[8] = *(const float4*)&Xg[k0 + 8];
    *(float4*)&xv[12] = *(const float4*)&Xg[k0 + 12];
    uint4 w0 = *(const uint4*)&Wg[k0];
    uint4 w1 = *(const uint4*)&Wg[k0 + 8];
    union { unsigned short us[16]; uint4 q[2]; } hb;
#pragma unroll
    for (int i = 0; i < 16; i++) hb.us[i] = f2bf_rne(xv[i]);
    __syncthreads();
    *(uint4*)&XsL[0] = hb.q[0];
    *(uint4*)&XsL[8] = hb.q[1];
    *(uint4*)&WsL[0] = w0;
    *(uint4*)&WsL[8] = w1;
    __syncthreads();
    bf16x8 af[4], bf[4];
#pragma unroll
    for (int i = 0; i < 4; i++) {
      af[i] = *(const bf16x8*)&Xs[(wr + 16 * i + fr) * LDK + fk];
      bf[i] = *(const bf16x8*)&Ws[(wc + 16 * i + fr) * LDK + fk];
    }
#pragma unroll
    for (int i = 0; i < 4; i++)
#pragma unroll
      for (int j = 0; j < 4; j++)
        acc[i][j] = __builtin_amdgcn_mfma_f32_16x16x32_bf16(af[i], bf[j],
                                                            acc[i][j], 0, 0, 0);
  }
  float bj[4];
#pragma unroll
  for (int j = 0; j < 4; j++) bj[j] = bias[n0 + wc + 16 * j + (l & 15)];
#pragma unroll
  for (int i = 0; i < 4; i++) {
#pragma unroll
    for (int r = 0; r < 4; r++) {
      int t = t0 + wr + 16 * i + (l >> 4) * 4 + r;
      unsigned short* vrow = Vbf + ((size_t)(b * 2048 + t)) * 512;
#pragma unroll
      for (int j = 0; j < 4; j++) {
        int d = n0 + wc + 16 * j + (l & 15);
        vrow[d] = f2bf_rne(acc[i][j][r] + bj[j]);
      }
    }
  }
}

// ---------------------------------------------------------------------------
// Plain-bf16 GEMM for output projection.
// ---------------------------------------------------------------------------
__global__ __launch_bounds__(256) void gemm_bf16_out(
    const unsigned short* __restrict__ Abf,
    const unsigned short* __restrict__ WThi, const float* __restrict__ bias,
    float* __restrict__ Y) {
  __shared__ __align__(16) unsigned short Ws[128 * LDK];
  __shared__ __align__(16) unsigned short Xs[128 * LDK];
  const int tid = threadIdx.x;
  const int n0 = blockIdx.x * 128;
  const int b = blockIdx.y >> 4;
  const int t0 = (blockIdx.y & 15) * 128;
  const int w = tid >> 6, l = tid & 63;
  const int wr = (w & 1) * 64;
  const int wc = (w >> 1) * 64;
  const int fr = l & 15, fk = (l >> 4) * 8;

  f32x4 acc[4][4];
#pragma unroll
  for (int i = 0; i < 4; i++)
#pragma unroll
    for (int j = 0; j < 4; j++) acc[i][j] = (f32x4)0.f;

  const int srow = tid >> 1, scol = (tid & 1) * 16;
  const unsigned short* Ag = Abf + ((size_t)(b * 2048 + t0 + srow)) * 512 + scol;
  const unsigned short* Wg = WThi + ((size_t)(n0 + srow)) * 512 + scol;
  unsigned short* XsL = &Xs[srow * LDK + scol];
  unsigned short* WsL = &Ws[srow * LDK + scol];

  for (int k0 = 0; k0 < 512; k0 += 32) {
    uint4 a0 = *(const uint4*)&Ag[k0];
    uint4 a1 = *(const uint4*)&Ag[k0 + 8];
    uint4 w0 = *(const uint4*)&Wg[k0];
    uint4 w1 = *(const uint4*)&Wg[k0 + 8];
    __syncthreads();
    *(uint4*)&XsL[0] = a0;
    *(uint4*)&XsL[8] = a1;
    *(uint4*)&WsL[0] = w0;
    *(uint4*)&WsL[8] = w1;
    __syncthreads();
    bf16x8 af[4], bf[4];
#pragma unroll
    for (int i = 0; i < 4; i++) {
      af[i] = *(const bf16x8*)&Xs[(wr + 16 * i + fr) * LDK + fk];
      bf[i] = *(const bf16x8*)&Ws[(wc + 16 * i + fr) * LDK + fk];
    }
#pragma unroll
    for (int i = 0; i < 4; i++)
#pragma unroll
      for (int j = 0; j < 4; j++)
        acc[i][j] = __builtin_amdgcn_mfma_f32_16x16x32_bf16(af[i], bf[j],
                                                            acc[i][j], 0, 0, 0);
  }
  float bj[4];
#pragma unroll
  for (int j = 0; j < 4; j++) bj[j] = bias[n0 + wc + 16 * j + (l & 15)];
#pragma unroll
  for (int i = 0; i < 4; i++) {
#pragma unroll
    for (int r = 0; r < 4; r++) {
      int t = t0 + wr + 16 * i + (l >> 4) * 4 + r;
      float* yrow = Y + ((size_t)(b * 2048 + t)) * 512;
#pragma unroll
      for (int j = 0; j < 4; j++) {
        int n = n0 + wc + 16 * j + (l & 15);
        yrow[n] = acc[i][j][r] + bj[j];
      }
    }
  }
}

// ---------------------------------------------------------------------------
// Radix-8 register FFT machinery (2048 = 8*8*8*4).
// ---------------------------------------------------------------------------
__device__ __forceinline__ float2 cadd(float2 a, float2 b) {
  return make_float2(a.x + b.x, a.y + b.y);
}
__device__ __forceinline__ float2 csub(float2 a, float2 b) {
  return make_float2(a.x - b.x, a.y - b.y);
}
__device__ __forceinline__ float2 cmulf(float2 a, float2 b) {
  return make_float2(a.x * b.x - a.y * b.y, a.x * b.y + a.y * b.x);
}
template <int SGN>  // -1 fwd (W = e^{-i...}), +1 inverse
__device__ __forceinline__ float2 mul_i(float2 a) {
  // multiply by SGN*i
  return (SGN < 0) ? make_float2(a.y, -a.x) : make_float2(-a.y, a.x);
}

template <int SGN>
__device__ __forceinline__ void dft4(float2 v[4]) {
  float2 b0 = cadd(v[0], v[2]);
  float2 b2 = csub(v[0], v[2]);
  float2 b1 = cadd(v[1], v[3]);
  float2 b3 = mul_i<SGN>(csub(v[1], v[3]));
  v[0] = cadd(b0, b1);
  v[2] = csub(b0, b1);
  v[1] = cadd(b2, b3);
  v[3] = csub(b2, b3);
}

template <int SGN>
__device__ __forceinline__ void dft8(float2 v[8]) {
  const float C = 0.70710678118654752f;
  float2 e[4], o[4];
#pragma unroll
  for (int i = 0; i < 4; i++) {
    e[i] = cadd(v[i], v[i + 4]);
    o[i] = csub(v[i], v[i + 4]);
  }
  {  // o[1] *= W8^1
    float s = o[1].x, t = o[1].y;
    o[1] = (SGN < 0) ? make_float2(C * (s + t), C * (t - s))
                     : make_float2(C * (s - t), C * (s + t));
  }
  o[2] = mul_i<SGN>(o[2]);  // o[2] *= W8^2
  {  // o[3] *= W8^3
    float s = o[3].x, t = o[3].y;
    o[3] = (SGN < 0) ? make_float2(C * (t - s), -C * (s + t))
                     : make_float2(-C * (s + t), C * (s - t));
  }
  dft4<SGN>(e);
  dft4<SGN>(o);
  v[0] = e[0]; v[2] = e[1]; v[4] = e[2]; v[6] = e[3];
  v[1] = o[0]; v[3] = o[1]; v[5] = o[2]; v[7] = o[3];
}

// out[r] *= T^r, T = e^{i*ang}; shared between the two interleaved FFTs.
__device__ __forceinline__ void twiddle8_pair(float2 vz[8], float2 vw[8],
                                              float ang) {
  float2 T;
  __sincosf(ang, &T.y, &T.x);
  float2 t = T;
  vz[1] = cmulf(vz[1], t);
  vw[1] = cmulf(vw[1], t);
#pragma unroll
  for (int r = 2; r < 8; r++) {
    t = cmulf(t, T);
    vz[r] = cmulf(vz[r], t);
    vw[r] = cmulf(vw[r], t);
  }
}
__device__ __forceinline__ void twiddle8_one(float2 v[8], float ang) {
  float2 T;
  __sincosf(ang, &T.y, &T.x);
  float2 t = T;
  v[1] = cmulf(v[1], t);
#pragma unroll
  for (int r = 2; r < 8; r++) {
    t = cmulf(t, T);
    v[r] = cmulf(v[r], t);
  }
}

// ---------------------------------------------------------------------------
// FFT correlate: per (b, feature-pair) block. qT,kT: [B,512,2048] fp32.
// attn written IN PLACE over qT rows. Radix 8,8,8,4 DIF; natural-order
// spectrum obtained for free via rev3-digit quad assignment in stage 4.
// ---------------------------------------------------------------------------
__global__ __launch_bounds__(256) void fft_correlate(
    float* __restrict__ qT, const float* __restrict__ kT) {
  __shared__ float2 ldsZ[2112];
  __shared__ float2 ldsW[2112];
  const int b = blockIdx.x;
  const int d0 = blockIdx.y * 2;
  const int tid = threadIdx.x;
  const size_t base = ((size_t)b * 512 + d0) * 2048;

  const float W1 = -6.28318530717958647692f / 2048.f;  // fwd base angle/idx
  const int j2 = tid & 31, j3 = tid & 3;
  const int s1 = tid >> 5, s2 = tid >> 2;
  // base-8 digit reverse of tid over 9 bits (involution on [0,512))
  const int f1 = ((tid & 7) << 6) | (tid & 56) | (tid >> 6);
  const int pt = tid + (tid >> 5);          // FFT_PAD(tid)
  const int b2 = 264 * s1 + j2;             // FFT_PAD(256*s1 + j2)
  const int b3 = 33 * s2 + j3;              // FFT_PAD(32*s2 + j3)

  float2 vz[8], vw[8];
#pragma unroll
  for (int r = 0; r < 8; r++) {
    int t = tid + (r << 8);
    vz[r] = make_float2(qT[base + t], qT[base + 2048 + t]);
    vw[r] = make_float2(kT[base + t], kT[base + 2048 + t]);
  }

  // ---- forward FFTs (q and k interleaved, twiddles shared) ----
  // stage 1: span 2048, radix 8; j = tid
  dft8<-1>(vz);
  dft8<-1>(vw);
  twiddle8_pair(vz, vw, W1 * (float)tid);
#pragma unroll
  for (int r = 0; r < 8; r++) {  // write p = 256*r + tid
    ldsZ[pt + 264 * r] = vz[r];
    ldsW[pt + 264 * r] = vw[r];
  }
  __syncthreads();
  // stage 2: span 256; read/write the same per-thread slot set (no sync betw.)
#pragma unroll
  for (int m = 0; m < 8; m++) {  // p = 256*s1 + j2 + 32*m
    vz[m] = ldsZ[b2 + 33 * m];
    vw[m] = ldsW[b2 + 33 * m];
  }
  dft8<-1>(vz);
  dft8<-1>(vw);
  twiddle8_pair(vz, vw, (W1 * 8.f) * (float)j2);
#pragma unroll
  for (int r = 0; r < 8; r++) {  // p = 256*s1 + 32*r + j2
    ldsZ[b2 + 33 * r] = vz[r];
    ldsW[b2 + 33 * r] = vw[r];
  }
  __syncthreads();
  // stage 3: span 32
#pragma unroll
  for (int m = 0; m < 8; m++) {  // p = 32*s2 + j3 + 4*m
    vz[m] = ldsZ[b3 + 4 * m];
    vw[m] = ldsW[b3 + 4 * m];
  }
  dft8<-1>(vz);
  dft8<-1>(vw);
  twiddle8_pair(vz, vw, (W1 * 64.f) * (float)j3);
#pragma unroll
  for (int r = 0; r < 8; r++) {  // p = 32*s2 + 4*r + j3
    ldsZ[b3 + 4 * r] = vz[r];
    ldsW[b3 + 4 * r] = vw[r];
  }
  __syncthreads();
  // stage 4: radix-4 on quads f1 and f1+4 -> outputs at k = tid + 256*m
  {
    float2 za[4], zb[4], wa[4], wb[4];
    const int pb = f1 << 2;
#pragma unroll
    for (int c = 0; c < 4; c++) {
      za[c] = ldsZ[FFT_PAD(pb + c)];
      zb[c] = ldsZ[FFT_PAD(pb + 16 + c)];
      wa[c] = ldsW[FFT_PAD(pb + c)];
      wb[c] = ldsW[FFT_PAD(pb + 16 + c)];
    }
    dft4<-1>(za);
    dft4<-1>(zb);
    dft4<-1>(wa);
    dft4<-1>(wb);
    __syncthreads();
#pragma unroll
    for (int c = 0; c < 4; c++) {
      ldsZ[pt + 528 * c] = za[c];        // k = tid + 512*c
      ldsZ[pt + 264 + 528 * c] = zb[c];  // k = tid + 256 + 512*c
      ldsW[pt + 528 * c] = wa[c];
      ldsW[pt + 264 + 528 * c] = wb[c];
    }
  }
  __syncthreads();

  // ---- pointwise: unpack two real spectra, cross product, repack ----
  float2 G[8];
#pragma unroll
  for (int r = 0; r < 8; r++) {
    int f = tid + (r << 8);
    int fn = (NFFT - f) & (NFFT - 1);
    float2 Zf = ldsZ[pt + 264 * r], Zn = ldsZ[FFT_PAD(fn)];
    float2 Wf = ldsW[pt + 264 * r], Wn = ldsW[FFT_PAD(fn)];
    float A1x = Zf.x + Zn.x, A1y = Zf.y - Zn.y;
    float B1x = Wf.x + Wn.x, B1y = Wn.y - Wf.y;
    float A2x = Zf.x - Zn.x, A2y = Zf.y + Zn.y;
    float B2x = Wf.x - Wn.x, B2y = -Wf.y - Wn.y;
    float p1x = A1x * B1x - A1y * B1y;
    float p1y = A1x * B1y + A1y * B1x;
    float p2x = A2x * B2x - A2y * B2y;
    float p2y = A2x * B2y + A2y * B2x;
    G[r] = make_float2(0.25f * (p1x - p2y), 0.25f * (p1y + p2x));
    (void)f;
  }
  __syncthreads();

  // ---- inverse FFT (true SGN=+1) on G, exchanges through ldsZ ----
  dft8<1>(G);
  twiddle8_one(G, (-W1) * (float)tid);
#pragma unroll
  for (int r = 0; r < 8; r++) ldsZ[pt + 264 * r] = G[r];
  __syncthreads();
#pragma unroll
  for (int m = 0; m < 8; m++) G[m] = ldsZ[b2 + 33 * m];
  dft8<1>(G);
  twiddle8_one(G, (-W1 * 8.f) * (float)j2);
#pragma unroll
  for (int r = 0; r < 8; r++) ldsZ[b2 + 33 * r] = G[r];
  __syncthreads();
#pragma unroll
  for (int m = 0; m < 8; m++) G[m] = ldsZ[b3 + 4 * m];
  dft8<1>(G);
  twiddle8_one(G, (-W1 * 64.f) * (float)j3);
#pragma unroll
  for (int r = 0; r < 8; r++) ldsZ[b3 + 4 * r] = G[r];
  __syncthreads();
  {
    float2 za[4], zb[4];
    const int pb = f1 << 2;
#pragma unroll
    for (int c = 0; c < 4; c++) {
      za[c] = ldsZ[FFT_PAD(pb + c)];
      zb[c] = ldsZ[FFT_PAD(pb + 16 + c)];
    }
    dft4<1>(za);
    dft4<1>(zb);
    const float scale = 1.0f / (float)NFFT;
#pragma unroll
    for (int c = 0; c < 4; c++) {
      int ta = tid + (c << 9);        // time index from quad f1
      int tb = ta + 256;              // time index from quad f1+4
      qT[base + ta] = za[c].x * scale;
      qT[base + 2048 + ta] = za[c].y * scale;
      qT[base + tb] = zb[c].x * scale;
      qT[base + 2048 + tb] = zb[c].y * scale;
    }
  }
}

// ---------------------------------------------------------------------------
// Column stats over d: mean (for top-k) + online softmax (max, expsum)
// ---------------------------------------------------------------------------
__global__ __launch_bounds__(256) void colstats_kernel(
    const float* __restrict__ attnT, float* __restrict__ mean,
    float2* __restrict__ stats) {
  const int b = blockIdx.x;
  const int t = blockIdx.y * 256 + threadIdx.x;
  const size_t base = (size_t)b * 512 * 2048 + t;
  float sum = 0.f, m = -1e30f, s = 0.f;
  for (int d = 0; d < 512; d++) {
    float a = attnT[base + (size_t)d * 2048];
    sum += a;
    float mn = fmaxf(m, a);
    s = s * __expf(m - mn) + __expf(a - mn);
    m = mn;
  }
  mean[b * 2048 + t] = sum * (1.f / 512.f);
  stats[b * 2048 + t] = make_float2(m, s);
}

// ---------------------------------------------------------------------------
// Top-15 per batch (iterative argmax, lowest-index tie-break)
// ---------------------------------------------------------------------------
__global__ __launch_bounds__(256) void topk_kernel(
    const float* __restrict__ mean, int* __restrict__ delays) {
  __shared__ float vals[2048];
  __shared__ float sv[256];
  __shared__ int si[256];
  const int b = blockIdx.x, tid = threadIdx.x;
#pragma unroll
  for (int r = 0; r < 8; r++)
    vals[tid + (r << 8)] = mean[b * 2048 + tid + (r << 8)];
  __syncthreads();
  for (int k = 0; k < 15; k++) {
    float bv = -1e30f;
    int bi = 1 << 30;
#pragma unroll
    for (int r = 0; r < 8; r++) {
      int i = (r << 8) + tid;
      float v = vals[i];
      if (v > bv || (v == bv && i < bi)) { bv = v; bi = i; }
    }
    sv[tid] = bv;
    si[tid] = bi;
    __syncthreads();
    for (int off = 128; off > 0; off >>= 1) {
      if (tid < off) {
        float v2 = sv[tid + off];
        int i2 = si[tid + off];
        if (v2 > sv[tid] || (v2 == sv[tid] && i2 < si[tid])) {
          sv[tid] = v2;
          si[tid] = i2;
        }
      }
      __syncthreads();
    }
    if (tid == 0) {
      delays[b * 15 + k] = si[0];
      vals[si[0]] = -1e30f;
    }
    __syncthreads();
  }
}

// ---------------------------------------------------------------------------
// Context: ctx[b][t][d] = softmax_d(attn)[d][t] * sum_k v[b][(t-dly_k)%T][d]
// ---------------------------------------------------------------------------
__global__ __launch_bounds__(256) void ctx_kernel(
    const float* __restrict__ attnT, const unsigned short* __restrict__ vbf,
    const float2* __restrict__ stats, const int* __restrict__ delays,
    unsigned short* __restrict__ ctx) {
  const int b = blockIdx.x;
  const int tb = blockIdx.y * 8;
  const int tid = threadIdx.x;
  __shared__ int dly[15];
  if (tid < 15) dly[tid] = delays[b * 15 + tid];
  __syncthreads();
  const size_t vbase = (size_t)b * 2048 * 512;
  const size_t abase = (size_t)b * 512 * 2048;
#pragma unroll
  for (int half = 0; half < 2; half++) {
    int d = half * 256 + tid;
    for (int tt = 0; tt < 8; tt++) {
      int t = tb + tt;
      float rolled = 0.f;
#pragma unroll
      for (int k = 0; k < 15; k++)
        rolled += bf2f(vbf[vbase + (size_t)((t - dly[k]) & 2047) * 512 + d]);
      float2 st = stats[b * 2048 + t];
      float a = attnT[abase + (size_t)d * 2048 + t];
      float p = __expf(a - st.x) / st.y;
      ctx[vbase + (size_t)t * 512 + d] = f2bf_rne(p * rolled);
    }
  }
}

// ---------------------------------------------------------------------------
extern "C" void kernel_launch(void* const* d_in, const int* in_sizes, int n_in,
                              void* d_out, int out_size, void* d_ws,
                              size_t ws_size, hipStream_t stream) {
  const float* query = (const float*)d_in[0];
  const float* key_in = (const float*)d_in[1];
  const float* value = (const float*)d_in[2];
  const float* Wq = (const float*)d_in[3];
  const float* bq = (const float*)d_in[4];
  const float* Wk = (const float*)d_in[5];
  const float* bk = (const float*)d_in[6];
  const float* Wv = (const float*)d_in[7];
  const float* bv = (const float*)d_in[8];
  const float* Wo = (const float*)d_in[9];
  const float* bo = (const float*)d_in[10];
  float* out = (float*)d_out;

  float* ws = (float*)d_ws;
  const size_t SZ = (size_t)32 * 512 * 2048;  // floats per [B,512,2048] tensor
  float* qT = ws;          // fp32 q -> attn (in place)
  float* kT = ws + SZ;     // fp32 k; REUSED after fft: vbf (first half) + ctx
  unsigned short* vbf = (unsigned short*)(ws + SZ);
  unsigned short* ctxbf = (unsigned short*)(ws + SZ + SZ / 2);
  unsigned short* wbuf = (unsigned short*)(ws + 2 * SZ);  // 2,097,152 ushorts
  float* mean = ws + 2 * SZ + 1048576;                    // 65536
  float2* stats = (float2*)(ws + 2 * SZ + 1048576 + 65536);  // 65536 float2
  int* delays = (int*)(ws + 2 * SZ + 1048576 + 65536 + 131072);

  const unsigned short* wq_hi = wbuf + 0 * 524288;
  const unsigned short* wq_lo = wq_hi + 262144;
  const unsigned short* wk_hi = wbuf + 1 * 524288;
  const unsigned short* wk_lo = wk_hi + 262144;
  const unsigned short* wv_hi = wbuf + 2 * 524288;
  const unsigned short* wo_hi = wbuf + 3 * 524288;

  wsplit_kernel<<<dim3(16, 16, 4), 256, 0, stream>>>(Wq, Wk, Wv, Wo, wbuf);

  proj_gemm_split<<<dim3(4, 512), 256, 0, stream>>>(query, wq_hi, wq_lo, bq, qT);
  proj_gemm_split<<<dim3(4, 512), 256, 0, stream>>>(key_in, wk_hi, wk_lo, bk, kT);

  fft_correlate<<<dim3(32, 256), 256, 0, stream>>>(qT, kT);

  // v projection AFTER fft (vbf aliases kT region)
  gemm_bf16_vproj<<<dim3(4, 512), 256, 0, stream>>>(value, wv_hi, bv, vbf);

  colstats_kernel<<<dim3(32, 8), 256, 0, stream>>>(qT, mean, stats);
  topk_kernel<<<32, 256, 0, stream>>>(mean, delays);
  ctx_kernel<<<dim3(32, 256), 256, 0, stream>>>(qT, vbf, stats, delays, ctxbf);

  gemm_bf16_out<<<dim3(4, 512), 256, 0, stream>>>(ctxbf, wo_hi, bo, out);
}

// Round 2
// 1055.764 us; speedup vs baseline: 1.3073x; 1.1411x over previous
//
#include <hip/hip_runtime.h>

#define NFFT 2048
#define LDK 40  // padded LDS row length in bf16 units (32 data + 8 pad)
#define FFT_PAD(p) ((p) + ((p) >> 5))

typedef __attribute__((ext_vector_type(8))) short bf16x8;
typedef __attribute__((ext_vector_type(4))) float f32x4;

__device__ __forceinline__ unsigned short f2bf_rne(float x) {
  unsigned u = __float_as_uint(x);
  return (unsigned short)((u + 0x7fffu + ((u >> 16) & 1u)) >> 16);
}
__device__ __forceinline__ float bf2f(unsigned short h) {
  return __uint_as_float(((unsigned)h) << 16);
}

// ---------------------------------------------------------------------------
// Weight split+transpose: W[k][n] fp32 -> WThi[n][k], WTlo[n][k] bf16.
// ---------------------------------------------------------------------------
__global__ __launch_bounds__(256) void wsplit_kernel(
    const float* __restrict__ W0, const float* __restrict__ W1,
    const float* __restrict__ W2, const float* __restrict__ W3,
    unsigned short* __restrict__ out) {
  __shared__ float tile[32][33];
  const float* W = (blockIdx.z == 0) ? W0
                   : (blockIdx.z == 1) ? W1
                   : (blockIdx.z == 2) ? W2 : W3;
  unsigned short* hi = out + (size_t)blockIdx.z * 524288;
  unsigned short* lo = hi + 262144;
  const int k0 = blockIdx.x * 32, n0 = blockIdx.y * 32;
  const int c = threadIdx.x & 31, r = threadIdx.x >> 5;
#pragma unroll
  for (int p = 0; p < 4; p++)
    tile[r + 8 * p][c] = W[(size_t)(k0 + r + 8 * p) * 512 + n0 + c];
  __syncthreads();
#pragma unroll
  for (int p = 0; p < 4; p++) {
    int nn = r + 8 * p;
    float x = tile[c][nn];
    unsigned u = __float_as_uint(x);
    unsigned short h = (unsigned short)(u >> 16);
    float hf = __uint_as_float(u & 0xffff0000u);
    unsigned short l = f2bf_rne(x - hf);
    hi[(size_t)(n0 + nn) * 512 + k0 + c] = h;
    lo[(size_t)(n0 + nn) * 512 + k0 + c] = l;
  }
}

// ---------------------------------------------------------------------------
// Split-bf16 projection GEMM (3-product, ~fp32 accuracy), TRANSPOSED output.
// ---------------------------------------------------------------------------
__global__ __launch_bounds__(256) void proj_gemm_split(
    const float* __restrict__ X, const unsigned short* __restrict__ WThi,
    const unsigned short* __restrict__ WTlo, const float* __restrict__ bias,
    float* __restrict__ YT) {
  __shared__ __align__(16) unsigned short Wh[128 * LDK];
  __shared__ __align__(16) unsigned short Wl[128 * LDK];
  __shared__ __align__(16) unsigned short Xh[128 * LDK];
  __shared__ __align__(16) unsigned short Xl[128 * LDK];
  const int tid = threadIdx.x;
  const int n0 = blockIdx.x * 128;
  const int b = blockIdx.y >> 4;
  const int t0 = (blockIdx.y & 15) * 128;
  const int w = tid >> 6, l = tid & 63;
  const int wn = (w & 1) * 64;
  const int wt = (w >> 1) * 64;
  const int fr = l & 15;
  const int fk = (l >> 4) * 8;

  f32x4 acc[4][4];
#pragma unroll
  for (int i = 0; i < 4; i++)
#pragma unroll
    for (int j = 0; j < 4; j++) acc[i][j] = (f32x4)0.f;

  const int srow = tid >> 1, scol = (tid & 1) * 16;
  const float* Xg = X + ((size_t)(b * 2048 + t0 + srow)) * 512 + scol;
  const unsigned short* Whg = WThi + ((size_t)(n0 + srow)) * 512 + scol;
  const unsigned short* Wlg = WTlo + ((size_t)(n0 + srow)) * 512 + scol;
  unsigned short* XhL = &Xh[srow * LDK + scol];
  unsigned short* XlL = &Xl[srow * LDK + scol];
  unsigned short* WhL = &Wh[srow * LDK + scol];
  unsigned short* WlL = &Wl[srow * LDK + scol];

  for (int k0 = 0; k0 < 512; k0 += 32) {
    float xv[16];
    *(float4*)&xv[0] = *(const float4*)&Xg[k0];
    *(float4*)&xv[4] = *(const float4*)&Xg[k0 + 4];
    *(float4*)&xv[8] = *(const float4*)&Xg[k0 + 8];
    *(float4*)&xv[12] = *(const float4*)&Xg[k0 + 12];
    uint4 wh0 = *(const uint4*)&Whg[k0];
    uint4 wh1 = *(const uint4*)&Whg[k0 + 8];
    uint4 wl0 = *(const uint4*)&Wlg[k0];
    uint4 wl1 = *(const uint4*)&Wlg[k0 + 8];
    union { unsigned short us[16]; uint4 q[2]; } hb, lb;
#pragma unroll
    for (int i = 0; i < 16; i++) {
      unsigned u = __float_as_uint(xv[i]);
      hb.us[i] = (unsigned short)(u >> 16);
      float hf = __uint_as_float(u & 0xffff0000u);
      lb.us[i] = f2bf_rne(xv[i] - hf);
    }
    __syncthreads();
    *(uint4*)&XhL[0] = hb.q[0];
    *(uint4*)&XhL[8] = hb.q[1];
    *(uint4*)&XlL[0] = lb.q[0];
    *(uint4*)&XlL[8] = lb.q[1];
    *(uint4*)&WhL[0] = wh0;
    *(uint4*)&WhL[8] = wh1;
    *(uint4*)&WlL[0] = wl0;
    *(uint4*)&WlL[8] = wl1;
    __syncthreads();
    bf16x8 ah[4], al[4], bh[4], bl[4];
#pragma unroll
    for (int i = 0; i < 4; i++) {
      ah[i] = *(const bf16x8*)&Wh[(wn + 16 * i + fr) * LDK + fk];
      al[i] = *(const bf16x8*)&Wl[(wn + 16 * i + fr) * LDK + fk];
      bh[i] = *(const bf16x8*)&Xh[(wt + 16 * i + fr) * LDK + fk];
      bl[i] = *(const bf16x8*)&Xl[(wt + 16 * i + fr) * LDK + fk];
    }
#pragma unroll
    for (int i = 0; i < 4; i++)
#pragma unroll
      for (int j = 0; j < 4; j++) {
        acc[i][j] = __builtin_amdgcn_mfma_f32_16x16x32_bf16(ah[i], bh[j],
                                                            acc[i][j], 0, 0, 0);
        acc[i][j] = __builtin_amdgcn_mfma_f32_16x16x32_bf16(al[i], bh[j],
                                                            acc[i][j], 0, 0, 0);
        acc[i][j] = __builtin_amdgcn_mfma_f32_16x16x32_bf16(ah[i], bl[j],
                                                            acc[i][j], 0, 0, 0);
      }
  }
  const size_t obase = (size_t)b * 512 * 2048;
#pragma unroll
  for (int i = 0; i < 4; i++) {
#pragma unroll
    for (int r = 0; r < 4; r++) {
      int n = n0 + wn + 16 * i + (l >> 4) * 4 + r;
      float bsc = bias[n];
      size_t row = obase + (size_t)n * 2048 + t0 + wt + (l & 15);
#pragma unroll
      for (int j = 0; j < 4; j++) YT[row + 16 * j] = acc[i][j][r] + bsc;
    }
  }
}

// ---------------------------------------------------------------------------
// Plain-bf16 GEMM for v projection.
// ---------------------------------------------------------------------------
__global__ __launch_bounds__(256) void gemm_bf16_vproj(
    const float* __restrict__ X, const unsigned short* __restrict__ WThi,
    const float* __restrict__ bias, unsigned short* __restrict__ Vbf) {
  __shared__ __align__(16) unsigned short Ws[128 * LDK];
  __shared__ __align__(16) unsigned short Xs[128 * LDK];
  const int tid = threadIdx.x;
  const int n0 = blockIdx.x * 128;
  const int b = blockIdx.y >> 4;
  const int t0 = (blockIdx.y & 15) * 128;
  const int w = tid >> 6, l = tid & 63;
  const int wr = (w & 1) * 64;
  const int wc = (w >> 1) * 64;
  const int fr = l & 15, fk = (l >> 4) * 8;

  f32x4 acc[4][4];
#pragma unroll
  for (int i = 0; i < 4; i++)
#pragma unroll
    for (int j = 0; j < 4; j++) acc[i][j] = (f32x4)0.f;

  const int srow = tid >> 1, scol = (tid & 1) * 16;
  const float* Xg = X + ((size_t)(b * 2048 + t0 + srow)) * 512 + scol;
  const unsigned short* Wg = WThi + ((size_t)(n0 + srow)) * 512 + scol;
  unsigned short* XsL = &Xs[srow * LDK + scol];
  unsigned short* WsL = &Ws[srow * LDK + scol];

  for (int k0 = 0; k0 < 512; k0 += 32) {
    float xv[16];
    *(float4*)&xv[0] = *(const float4*)&Xg[k0];
    *(float4*)&xv[4] = *(const float4*)&Xg[k0 + 4];
    *(float4*)&xv[8] = *(const float4*)&Xg[k0 + 8];
    *(float4*)&xv[12] = *(const float4*)&Xg[k0 + 12];
    uint4 w0 = *(const uint4*)&Wg[k0];
    uint4 w1 = *(const uint4*)&Wg[k0 + 8];
    union { unsigned short us[16]; uint4 q[2]; } hb;
#pragma unroll
    for (int i = 0; i < 16; i++) hb.us[i] = f2bf_rne(xv[i]);
    __syncthreads();
    *(uint4*)&XsL[0] = hb.q[0];
    *(uint4*)&XsL[8] = hb.q[1];
    *(uint4*)&WsL[0] = w0;
    *(uint4*)&WsL[8] = w1;
    __syncthreads();
    bf16x8 af[4], bf[4];
#pragma unroll
    for (int i = 0; i < 4; i++) {
      af[i] = *(const bf16x8*)&Xs[(wr + 16 * i + fr) * LDK + fk];
      bf[i] = *(const bf16x8*)&Ws[(wc + 16 * i + fr) * LDK + fk];
    }
#pragma unroll
    for (int i = 0; i < 4; i++)
#pragma unroll
      for (int j = 0; j < 4; j++)
        acc[i][j] = __builtin_amdgcn_mfma_f32_16x16x32_bf16(af[i], bf[j],
                                                            acc[i][j], 0, 0, 0);
  }
  float bj[4];
#pragma unroll
  for (int j = 0; j < 4; j++) bj[j] = bias[n0 + wc + 16 * j + (l & 15)];
#pragma unroll
  for (int i = 0; i < 4; i++) {
#pragma unroll
    for (int r = 0; r < 4; r++) {
      int t = t0 + wr + 16 * i + (l >> 4) * 4 + r;
      unsigned short* vrow = Vbf + ((size_t)(b * 2048 + t)) * 512;
#pragma unroll
      for (int j = 0; j < 4; j++) {
        int d = n0 + wc + 16 * j + (l & 15);
        vrow[d] = f2bf_rne(acc[i][j][r] + bj[j]);
      }
    }
  }
}

// ---------------------------------------------------------------------------
// Plain-bf16 GEMM for output projection.
// ---------------------------------------------------------------------------
__global__ __launch_bounds__(256) void gemm_bf16_out(
    const unsigned short* __restrict__ Abf,
    const unsigned short* __restrict__ WThi, const float* __restrict__ bias,
    float* __restrict__ Y) {
  __shared__ __align__(16) unsigned short Ws[128 * LDK];
  __shared__ __align__(16) unsigned short Xs[128 * LDK];
  const int tid = threadIdx.x;
  const int n0 = blockIdx.x * 128;
  const int b = blockIdx.y >> 4;
  const int t0 = (blockIdx.y & 15) * 128;
  const int w = tid >> 6, l = tid & 63;
  const int wr = (w & 1) * 64;
  const int wc = (w >> 1) * 64;
  const int fr = l & 15, fk = (l >> 4) * 8;

  f32x4 acc[4][4];
#pragma unroll
  for (int i = 0; i < 4; i++)
#pragma unroll
    for (int j = 0; j < 4; j++) acc[i][j] = (f32x4)0.f;

  const int srow = tid >> 1, scol = (tid & 1) * 16;
  const unsigned short* Ag = Abf + ((size_t)(b * 2048 + t0 + srow)) * 512 + scol;
  const unsigned short* Wg = WThi + ((size_t)(n0 + srow)) * 512 + scol;
  unsigned short* XsL = &Xs[srow * LDK + scol];
  unsigned short* WsL = &Ws[srow * LDK + scol];

  for (int k0 = 0; k0 < 512; k0 += 32) {
    uint4 a0 = *(const uint4*)&Ag[k0];
    uint4 a1 = *(const uint4*)&Ag[k0 + 8];
    uint4 w0 = *(const uint4*)&Wg[k0];
    uint4 w1 = *(const uint4*)&Wg[k0 + 8];
    __syncthreads();
    *(uint4*)&XsL[0] = a0;
    *(uint4*)&XsL[8] = a1;
    *(uint4*)&WsL[0] = w0;
    *(uint4*)&WsL[8] = w1;
    __syncthreads();
    bf16x8 af[4], bf[4];
#pragma unroll
    for (int i = 0; i < 4; i++) {
      af[i] = *(const bf16x8*)&Xs[(wr + 16 * i + fr) * LDK + fk];
      bf[i] = *(const bf16x8*)&Ws[(wc + 16 * i + fr) * LDK + fk];
    }
#pragma unroll
    for (int i = 0; i < 4; i++)
#pragma unroll
      for (int j = 0; j < 4; j++)
        acc[i][j] = __builtin_amdgcn_mfma_f32_16x16x32_bf16(af[i], bf[j],
                                                            acc[i][j], 0, 0, 0);
  }
  float bj[4];
#pragma unroll
  for (int j = 0; j < 4; j++) bj[j] = bias[n0 + wc + 16 * j + (l & 15)];
#pragma unroll
  for (int i = 0; i < 4; i++) {
#pragma unroll
    for (int r = 0; r < 4; r++) {
      int t = t0 + wr + 16 * i + (l >> 4) * 4 + r;
      float* yrow = Y + ((size_t)(b * 2048 + t)) * 512;
#pragma unroll
      for (int j = 0; j < 4; j++) {
        int n = n0 + wc + 16 * j + (l & 15);
        yrow[n] = acc[i][j][r] + bj[j];
      }
    }
  }
}

// ---------------------------------------------------------------------------
// Radix-8 register FFT machinery (2048 = 8*8*8*4).
// ---------------------------------------------------------------------------
__device__ __forceinline__ float2 cadd(float2 a, float2 b) {
  return make_float2(a.x + b.x, a.y + b.y);
}
__device__ __forceinline__ float2 csub(float2 a, float2 b) {
  return make_float2(a.x - b.x, a.y - b.y);
}
__device__ __forceinline__ float2 cmulf(float2 a, float2 b) {
  return make_float2(a.x * b.x - a.y * b.y, a.x * b.y + a.y * b.x);
}
template <int SGN>  // -1 fwd (W = e^{-i...}), +1 inverse
__device__ __forceinline__ float2 mul_i(float2 a) {
  return (SGN < 0) ? make_float2(a.y, -a.x) : make_float2(-a.y, a.x);
}

template <int SGN>
__device__ __forceinline__ void dft4(float2 v[4]) {
  float2 b0 = cadd(v[0], v[2]);
  float2 b2 = csub(v[0], v[2]);
  float2 b1 = cadd(v[1], v[3]);
  float2 b3 = mul_i<SGN>(csub(v[1], v[3]));
  v[0] = cadd(b0, b1);
  v[2] = csub(b0, b1);
  v[1] = cadd(b2, b3);
  v[3] = csub(b2, b3);
}

template <int SGN>
__device__ __forceinline__ void dft8(float2 v[8]) {
  const float C = 0.70710678118654752f;
  float2 e[4], o[4];
#pragma unroll
  for (int i = 0; i < 4; i++) {
    e[i] = cadd(v[i], v[i + 4]);
    o[i] = csub(v[i], v[i + 4]);
  }
  {
    float s = o[1].x, t = o[1].y;
    o[1] = (SGN < 0) ? make_float2(C * (s + t), C * (t - s))
                     : make_float2(C * (s - t), C * (s + t));
  }
  o[2] = mul_i<SGN>(o[2]);
  {
    float s = o[3].x, t = o[3].y;
    o[3] = (SGN < 0) ? make_float2(C * (t - s), -C * (s + t))
                     : make_float2(-C * (s + t), C * (s - t));
  }
  dft4<SGN>(e);
  dft4<SGN>(o);
  v[0] = e[0]; v[2] = e[1]; v[4] = e[2]; v[6] = e[3];
  v[1] = o[0]; v[3] = o[1]; v[5] = o[2]; v[7] = o[3];
}

__device__ __forceinline__ void twiddle8_pair(float2 vz[8], float2 vw[8],
                                              float ang) {
  float2 T;
  __sincosf(ang, &T.y, &T.x);
  float2 t = T;
  vz[1] = cmulf(vz[1], t);
  vw[1] = cmulf(vw[1], t);
#pragma unroll
  for (int r = 2; r < 8; r++) {
    t = cmulf(t, T);
    vz[r] = cmulf(vz[r], t);
    vw[r] = cmulf(vw[r], t);
  }
}
__device__ __forceinline__ void twiddle8_one(float2 v[8], float ang) {
  float2 T;
  __sincosf(ang, &T.y, &T.x);
  float2 t = T;
  v[1] = cmulf(v[1], t);
#pragma unroll
  for (int r = 2; r < 8; r++) {
    t = cmulf(t, T);
    v[r] = cmulf(v[r], t);
  }
}

// ---------------------------------------------------------------------------
// FFT correlate: per (b, feature-pair) block. qT,kT: [B,512,2048] fp32.
// attn written IN PLACE over qT rows. Radix 8,8,8,4 DIF; natural-order
// spectrum obtained for free via rev3-digit quad assignment in stage 4.
// ---------------------------------------------------------------------------
__global__ __launch_bounds__(256) void fft_correlate(
    float* __restrict__ qT, const float* __restrict__ kT) {
  __shared__ float2 ldsZ[2112];
  __shared__ float2 ldsW[2112];
  const int b = blockIdx.x;
  const int d0 = blockIdx.y * 2;
  const int tid = threadIdx.x;
  const size_t base = ((size_t)b * 512 + d0) * 2048;

  const float W1 = -6.28318530717958647692f / 2048.f;
  const int j2 = tid & 31, j3 = tid & 3;
  const int s1 = tid >> 5, s2 = tid >> 2;
  const int f1 = ((tid & 7) << 6) | (tid & 56) | (tid >> 6);
  const int pt = tid + (tid >> 5);
  const int b2 = 264 * s1 + j2;
  const int b3 = 33 * s2 + j3;

  float2 vz[8], vw[8];
#pragma unroll
  for (int r = 0; r < 8; r++) {
    int t = tid + (r << 8);
    vz[r] = make_float2(qT[base + t], qT[base + 2048 + t]);
    vw[r] = make_float2(kT[base + t], kT[base + 2048 + t]);
  }

  dft8<-1>(vz);
  dft8<-1>(vw);
  twiddle8_pair(vz, vw, W1 * (float)tid);
#pragma unroll
  for (int r = 0; r < 8; r++) {
    ldsZ[pt + 264 * r] = vz[r];
    ldsW[pt + 264 * r] = vw[r];
  }
  __syncthreads();
#pragma unroll
  for (int m = 0; m < 8; m++) {
    vz[m] = ldsZ[b2 + 33 * m];
    vw[m] = ldsW[b2 + 33 * m];
  }
  dft8<-1>(vz);
  dft8<-1>(vw);
  twiddle8_pair(vz, vw, (W1 * 8.f) * (float)j2);
#pragma unroll
  for (int r = 0; r < 8; r++) {
    ldsZ[b2 + 33 * r] = vz[r];
    ldsW[b2 + 33 * r] = vw[r];
  }
  __syncthreads();
#pragma unroll
  for (int m = 0; m < 8; m++) {
    vz[m] = ldsZ[b3 + 4 * m];
    vw[m] = ldsW[b3 + 4 * m];
  }
  dft8<-1>(vz);
  dft8<-1>(vw);
  twiddle8_pair(vz, vw, (W1 * 64.f) * (float)j3);
#pragma unroll
  for (int r = 0; r < 8; r++) {
    ldsZ[b3 + 4 * r] = vz[r];
    ldsW[b3 + 4 * r] = vw[r];
  }
  __syncthreads();
  {
    float2 za[4], zb[4], wa[4], wb[4];
    const int pb = f1 << 2;
#pragma unroll
    for (int c = 0; c < 4; c++) {
      za[c] = ldsZ[FFT_PAD(pb + c)];
      zb[c] = ldsZ[FFT_PAD(pb + 16 + c)];
      wa[c] = ldsW[FFT_PAD(pb + c)];
      wb[c] = ldsW[FFT_PAD(pb + 16 + c)];
    }
    dft4<-1>(za);
    dft4<-1>(zb);
    dft4<-1>(wa);
    dft4<-1>(wb);
    __syncthreads();
#pragma unroll
    for (int c = 0; c < 4; c++) {
      ldsZ[pt + 528 * c] = za[c];
      ldsZ[pt + 264 + 528 * c] = zb[c];
      ldsW[pt + 528 * c] = wa[c];
      ldsW[pt + 264 + 528 * c] = wb[c];
    }
  }
  __syncthreads();

  float2 G[8];
#pragma unroll
  for (int r = 0; r < 8; r++) {
    int f = tid + (r << 8);
    int fn = (NFFT - f) & (NFFT - 1);
    float2 Zf = ldsZ[pt + 264 * r], Zn = ldsZ[FFT_PAD(fn)];
    float2 Wf = ldsW[pt + 264 * r], Wn = ldsW[FFT_PAD(fn)];
    float A1x = Zf.x + Zn.x, A1y = Zf.y - Zn.y;
    float B1x = Wf.x + Wn.x, B1y = Wn.y - Wf.y;
    float A2x = Zf.x - Zn.x, A2y = Zf.y + Zn.y;
    float B2x = Wf.x - Wn.x, B2y = -Wf.y - Wn.y;
    float p1x = A1x * B1x - A1y * B1y;
    float p1y = A1x * B1y + A1y * B1x;
    float p2x = A2x * B2x - A2y * B2y;
    float p2y = A2x * B2y + A2y * B2x;
    G[r] = make_float2(0.25f * (p1x - p2y), 0.25f * (p1y + p2x));
    (void)f;
  }
  __syncthreads();

  dft8<1>(G);
  twiddle8_one(G, (-W1) * (float)tid);
#pragma unroll
  for (int r = 0; r < 8; r++) ldsZ[pt + 264 * r] = G[r];
  __syncthreads();
#pragma unroll
  for (int m = 0; m < 8; m++) G[m] = ldsZ[b2 + 33 * m];
  dft8<1>(G);
  twiddle8_one(G, (-W1 * 8.f) * (float)j2);
#pragma unroll
  for (int r = 0; r < 8; r++) ldsZ[b2 + 33 * r] = G[r];
  __syncthreads();
#pragma unroll
  for (int m = 0; m < 8; m++) G[m] = ldsZ[b3 + 4 * m];
  dft8<1>(G);
  twiddle8_one(G, (-W1 * 64.f) * (float)j3);
#pragma unroll
  for (int r = 0; r < 8; r++) ldsZ[b3 + 4 * r] = G[r];
  __syncthreads();
  {
    float2 za[4], zb[4];
    const int pb = f1 << 2;
#pragma unroll
    for (int c = 0; c < 4; c++) {
      za[c] = ldsZ[FFT_PAD(pb + c)];
      zb[c] = ldsZ[FFT_PAD(pb + 16 + c)];
    }
    dft4<1>(za);
    dft4<1>(zb);
    const float scale = 1.0f / (float)NFFT;
#pragma unroll
    for (int c = 0; c < 4; c++) {
      int ta = tid + (c << 9);
      int tb = ta + 256;
      qT[base + ta] = za[c].x * scale;
      qT[base + 2048 + ta] = za[c].y * scale;
      qT[base + tb] = zb[c].x * scale;
      qT[base + 2048 + tb] = zb[c].y * scale;
    }
  }
}

// ---------------------------------------------------------------------------
// Column stats over d: mean (for top-k) + online softmax (max, expsum)
// ---------------------------------------------------------------------------
__global__ __launch_bounds__(256) void colstats_kernel(
    const float* __restrict__ attnT, float* __restrict__ mean,
    float2* __restrict__ stats) {
  const int b = blockIdx.x;
  const int t = blockIdx.y * 256 + threadIdx.x;
  const size_t base = (size_t)b * 512 * 2048 + t;
  float sum = 0.f, m = -1e30f, s = 0.f;
  for (int d = 0; d < 512; d++) {
    float a = attnT[base + (size_t)d * 2048];
    sum += a;
    float mn = fmaxf(m, a);
    s = s * __expf(m - mn) + __expf(a - mn);
    m = mn;
  }
  mean[b * 2048 + t] = sum * (1.f / 512.f);
  stats[b * 2048 + t] = make_float2(m, s);
}

// ---------------------------------------------------------------------------
// Top-15 per batch (iterative argmax, lowest-index tie-break)
// ---------------------------------------------------------------------------
__global__ __launch_bounds__(256) void topk_kernel(
    const float* __restrict__ mean, int* __restrict__ delays) {
  __shared__ float vals[2048];
  __shared__ float sv[256];
  __shared__ int si[256];
  const int b = blockIdx.x, tid = threadIdx.x;
#pragma unroll
  for (int r = 0; r < 8; r++)
    vals[tid + (r << 8)] = mean[b * 2048 + tid + (r << 8)];
  __syncthreads();
  for (int k = 0; k < 15; k++) {
    float bv = -1e30f;
    int bi = 1 << 30;
#pragma unroll
    for (int r = 0; r < 8; r++) {
      int i = (r << 8) + tid;
      float v = vals[i];
      if (v > bv || (v == bv && i < bi)) { bv = v; bi = i; }
    }
    sv[tid] = bv;
    si[tid] = bi;
    __syncthreads();
    for (int off = 128; off > 0; off >>= 1) {
      if (tid < off) {
        float v2 = sv[tid + off];
        int i2 = si[tid + off];
        if (v2 > sv[tid] || (v2 == sv[tid] && i2 < si[tid])) {
          sv[tid] = v2;
          si[tid] = i2;
        }
      }
      __syncthreads();
    }
    if (tid == 0) {
      delays[b * 15 + k] = si[0];
      vals[si[0]] = -1e30f;
    }
    __syncthreads();
  }
}

// ---------------------------------------------------------------------------
// Context: ctx[b][t][d] = softmax_d(attn)[d][t] * sum_k v[b][(t-dly_k)%T][d]
// Tiled: block = (b, 64-t tile); d in 64-wide chunks. attn staged through a
// padded LDS tile (coalesced along t); v read as 2x uint4 per delay; XCD-
// affine swizzle keeps all tiles of one b on one XCD (v L2 residency).
// ---------------------------------------------------------------------------
__global__ __launch_bounds__(256) void ctx_kernel(
    const float* __restrict__ attnT, const unsigned short* __restrict__ vbf,
    const float2* __restrict__ stats, const int* __restrict__ delays,
    unsigned short* __restrict__ ctx) {
  __shared__ float atile[64][65];
  __shared__ int dly[15];
  const int lin = blockIdx.x;
  const int g = lin >> 8;              // b-group of 8
  const int r = lin & 255;
  const int b = g * 8 + (r & 7);       // XCD = lin % 8 = b % 8
  const int tb = (r >> 3) * 64;        // t-tile base
  const int tid = threadIdx.x;
  if (tid < 15) dly[tid] = delays[b * 15 + tid];
  __syncthreads();

  const int tl = tid >> 2;             // local t / load row (0..63)
  const int dq = (tid & 3) * 16;       // d-sub base within 64-chunk
  const int tq = (tid & 3) * 4;        // t-sub base for load phase
  const int t = tb + tl;
  const float2 st = stats[b * 2048 + t];
  const float m = st.x, inv_s = 1.f / st.y;

  int rowoff[15];
#pragma unroll
  for (int k = 0; k < 15; k++)
    rowoff[k] = ((t - dly[k]) & 2047) * 512;

  const size_t vbase = (size_t)b * 2048 * 512;
  const size_t abase = (size_t)b * 512 * 2048;

  for (int d0 = 0; d0 < 512; d0 += 64) {
    __syncthreads();  // previous chunk's atile reads complete
#pragma unroll
    for (int tt = 0; tt < 4; tt++) {
      float4 a4 = *(const float4*)&attnT[abase + (size_t)(d0 + tl) * 2048 +
                                         tb + tt * 16 + tq];
      atile[tt * 16 + tq + 0][tl] = a4.x;
      atile[tt * 16 + tq + 1][tl] = a4.y;
      atile[tt * 16 + tq + 2][tl] = a4.z;
      atile[tt * 16 + tq + 3][tl] = a4.w;
    }
    __syncthreads();

    float rolled[16];
#pragma unroll
    for (int i = 0; i < 16; i++) rolled[i] = 0.f;
#pragma unroll
    for (int k = 0; k < 15; k++) {
      const uint4* vp = (const uint4*)(vbf + vbase + rowoff[k] + d0 + dq);
      uint4 v0 = vp[0], v1 = vp[1];
      unsigned uu[8] = {v0.x, v0.y, v0.z, v0.w, v1.x, v1.y, v1.z, v1.w};
#pragma unroll
      for (int w = 0; w < 8; w++) {
        rolled[2 * w + 0] += __uint_as_float(uu[w] << 16);
        rolled[2 * w + 1] += __uint_as_float(uu[w] & 0xffff0000u);
      }
    }

    union { unsigned short us[16]; uint4 q[2]; } ob;
#pragma unroll
    for (int i = 0; i < 16; i++) {
      float a = atile[tl][dq + i];
      float p = __expf(a - m) * inv_s;
      ob.us[i] = f2bf_rne(p * rolled[i]);
    }
    uint4* op = (uint4*)(ctx + vbase + (size_t)t * 512 + d0 + dq);
    op[0] = ob.q[0];
    op[1] = ob.q[1];
  }
}

// ---------------------------------------------------------------------------
extern "C" void kernel_launch(void* const* d_in, const int* in_sizes, int n_in,
                              void* d_out, int out_size, void* d_ws,
                              size_t ws_size, hipStream_t stream) {
  const float* query = (const float*)d_in[0];
  const float* key_in = (const float*)d_in[1];
  const float* value = (const float*)d_in[2];
  const float* Wq = (const float*)d_in[3];
  const float* bq = (const float*)d_in[4];
  const float* Wk = (const float*)d_in[5];
  const float* bk = (const float*)d_in[6];
  const float* Wv = (const float*)d_in[7];
  const float* bv = (const float*)d_in[8];
  const float* Wo = (const float*)d_in[9];
  const float* bo = (const float*)d_in[10];
  float* out = (float*)d_out;

  float* ws = (float*)d_ws;
  const size_t SZ = (size_t)32 * 512 * 2048;  // floats per [B,512,2048] tensor
  float* qT = ws;          // fp32 q -> attn (in place)
  float* kT = ws + SZ;     // fp32 k; REUSED after fft: vbf (first half) + ctx
  unsigned short* vbf = (unsigned short*)(ws + SZ);
  unsigned short* ctxbf = (unsigned short*)(ws + SZ + SZ / 2);
  unsigned short* wbuf = (unsigned short*)(ws + 2 * SZ);  // 2,097,152 ushorts
  float* mean = ws + 2 * SZ + 1048576;                    // 65536
  float2* stats = (float2*)(ws + 2 * SZ + 1048576 + 65536);  // 65536 float2
  int* delays = (int*)(ws + 2 * SZ + 1048576 + 65536 + 131072);

  const unsigned short* wq_hi = wbuf + 0 * 524288;
  const unsigned short* wq_lo = wq_hi + 262144;
  const unsigned short* wk_hi = wbuf + 1 * 524288;
  const unsigned short* wk_lo = wk_hi + 262144;
  const unsigned short* wv_hi = wbuf + 2 * 524288;
  const unsigned short* wo_hi = wbuf + 3 * 524288;

  wsplit_kernel<<<dim3(16, 16, 4), 256, 0, stream>>>(Wq, Wk, Wv, Wo, wbuf);

  proj_gemm_split<<<dim3(4, 512), 256, 0, stream>>>(query, wq_hi, wq_lo, bq, qT);
  proj_gemm_split<<<dim3(4, 512), 256, 0, stream>>>(key_in, wk_hi, wk_lo, bk, kT);

  fft_correlate<<<dim3(32, 256), 256, 0, stream>>>(qT, kT);

  // v projection AFTER fft (vbf aliases kT region)
  gemm_bf16_vproj<<<dim3(4, 512), 256, 0, stream>>>(value, wv_hi, bv, vbf);

  colstats_kernel<<<dim3(32, 8), 256, 0, stream>>>(qT, mean, stats);
  topk_kernel<<<32, 256, 0, stream>>>(mean, delays);
  ctx_kernel<<<1024, 256, 0, stream>>>(qT, vbf, stats, delays, ctxbf);

  gemm_bf16_out<<<dim3(4, 512), 256, 0, stream>>>(ctxbf, wo_hi, bo, out);
}

// Round 3
// 984.480 us; speedup vs baseline: 1.4019x; 1.0724x over previous
//
#include <hip/hip_runtime.h>

#define NFFT 2048
#define LDK 40  // padded LDS row length in bf16 units (32 data + 8 pad)
#define FFT_PAD(p) ((p) + ((p) >> 5))

typedef __attribute__((ext_vector_type(8))) short bf16x8;
typedef __attribute__((ext_vector_type(4))) float f32x4;

__device__ __forceinline__ unsigned short f2bf_rne(float x) {
  unsigned u = __float_as_uint(x);
  return (unsigned short)((u + 0x7fffu + ((u >> 16) & 1u)) >> 16);
}
__device__ __forceinline__ float bf2f(unsigned short h) {
  return __uint_as_float(((unsigned)h) << 16);
}

// Decode 1D block id -> (n-tile, y) with XCD affinity: the 4 n-tiles that
// share one X tile (same y) land on the SAME XCD (lin%8 preserved), adjacent
// in dispatch order.
__device__ __forceinline__ void gemm_decode(int lin, int& n0, int& b,
                                            int& t0) {
  const int xcd = lin & 7;
  const int j = lin >> 3;
  const int nblk = j & 3;
  const int y = (j >> 2) * 8 + xcd;
  n0 = nblk * 128;
  b = y >> 4;
  t0 = (y & 15) * 128;
}

// ---------------------------------------------------------------------------
// Weight split+transpose: W[k][n] fp32 -> WThi[n][k], WTlo[n][k] bf16.
// ---------------------------------------------------------------------------
__global__ __launch_bounds__(256) void wsplit_kernel(
    const float* __restrict__ W0, const float* __restrict__ W1,
    const float* __restrict__ W2, const float* __restrict__ W3,
    unsigned short* __restrict__ out) {
  __shared__ float tile[32][33];
  const float* W = (blockIdx.z == 0) ? W0
                   : (blockIdx.z == 1) ? W1
                   : (blockIdx.z == 2) ? W2 : W3;
  unsigned short* hi = out + (size_t)blockIdx.z * 524288;
  unsigned short* lo = hi + 262144;
  const int k0 = blockIdx.x * 32, n0 = blockIdx.y * 32;
  const int c = threadIdx.x & 31, r = threadIdx.x >> 5;
#pragma unroll
  for (int p = 0; p < 4; p++)
    tile[r + 8 * p][c] = W[(size_t)(k0 + r + 8 * p) * 512 + n0 + c];
  __syncthreads();
#pragma unroll
  for (int p = 0; p < 4; p++) {
    int nn = r + 8 * p;
    float x = tile[c][nn];
    unsigned u = __float_as_uint(x);
    unsigned short h = (unsigned short)(u >> 16);
    float hf = __uint_as_float(u & 0xffff0000u);
    unsigned short l = f2bf_rne(x - hf);
    hi[(size_t)(n0 + nn) * 512 + k0 + c] = h;
    lo[(size_t)(n0 + nn) * 512 + k0 + c] = l;
  }
}

// ---------------------------------------------------------------------------
// Split-bf16 projection GEMM (3-product, ~fp32 accuracy), TRANSPOSED output.
// Pipelined: loads for tile k+1 issued before MFMA of tile k.
// ---------------------------------------------------------------------------
__global__ __launch_bounds__(256) void proj_gemm_split(
    const float* __restrict__ X, const unsigned short* __restrict__ WThi,
    const unsigned short* __restrict__ WTlo, const float* __restrict__ bias,
    float* __restrict__ YT) {
  __shared__ __align__(16) unsigned short Wh[128 * LDK];
  __shared__ __align__(16) unsigned short Wl[128 * LDK];
  __shared__ __align__(16) unsigned short Xh[128 * LDK];
  __shared__ __align__(16) unsigned short Xl[128 * LDK];
  const int tid = threadIdx.x;
  int n0, b, t0;
  gemm_decode(blockIdx.x, n0, b, t0);
  const int w = tid >> 6, l = tid & 63;
  const int wn = (w & 1) * 64;
  const int wt = (w >> 1) * 64;
  const int fr = l & 15;
  const int fk = (l >> 4) * 8;

  f32x4 acc[4][4];
#pragma unroll
  for (int i = 0; i < 4; i++)
#pragma unroll
    for (int j = 0; j < 4; j++) acc[i][j] = (f32x4)0.f;

  const int srow = tid >> 1, scol = (tid & 1) * 16;
  const float* Xg = X + ((size_t)(b * 2048 + t0 + srow)) * 512 + scol;
  const unsigned short* Whg = WThi + ((size_t)(n0 + srow)) * 512 + scol;
  const unsigned short* Wlg = WTlo + ((size_t)(n0 + srow)) * 512 + scol;
  unsigned short* XhL = &Xh[srow * LDK + scol];
  unsigned short* XlL = &Xl[srow * LDK + scol];
  unsigned short* WhL = &Wh[srow * LDK + scol];
  unsigned short* WlL = &Wl[srow * LDK + scol];

  float xv[16];
  uint4 wh0, wh1, wl0, wl1;
  *(float4*)&xv[0] = *(const float4*)&Xg[0];
  *(float4*)&xv[4] = *(const float4*)&Xg[4];
  *(float4*)&xv[8] = *(const float4*)&Xg[8];
  *(float4*)&xv[12] = *(const float4*)&Xg[12];
  wh0 = *(const uint4*)&Whg[0];
  wh1 = *(const uint4*)&Whg[8];
  wl0 = *(const uint4*)&Wlg[0];
  wl1 = *(const uint4*)&Wlg[8];

  for (int k0 = 0; k0 < 512; k0 += 32) {
    union { unsigned short us[16]; uint4 q[2]; } hb, lb;
#pragma unroll
    for (int i = 0; i < 16; i++) {
      unsigned u = __float_as_uint(xv[i]);
      hb.us[i] = (unsigned short)(u >> 16);
      float hf = __uint_as_float(u & 0xffff0000u);
      lb.us[i] = f2bf_rne(xv[i] - hf);
    }
    __syncthreads();
    *(uint4*)&XhL[0] = hb.q[0];
    *(uint4*)&XhL[8] = hb.q[1];
    *(uint4*)&XlL[0] = lb.q[0];
    *(uint4*)&XlL[8] = lb.q[1];
    *(uint4*)&WhL[0] = wh0;
    *(uint4*)&WhL[8] = wh1;
    *(uint4*)&WlL[0] = wl0;
    *(uint4*)&WlL[8] = wl1;
    __syncthreads();
    const int k1 = k0 + 32;
    if (k1 < 512) {  // issue next-tile loads; latency hides under MFMA
      *(float4*)&xv[0] = *(const float4*)&Xg[k1];
      *(float4*)&xv[4] = *(const float4*)&Xg[k1 + 4];
      *(float4*)&xv[8] = *(const float4*)&Xg[k1 + 8];
      *(float4*)&xv[12] = *(const float4*)&Xg[k1 + 12];
      wh0 = *(const uint4*)&Whg[k1];
      wh1 = *(const uint4*)&Whg[k1 + 8];
      wl0 = *(const uint4*)&Wlg[k1];
      wl1 = *(const uint4*)&Wlg[k1 + 8];
    }
    bf16x8 ah[4], al[4], bh[4], bl[4];
#pragma unroll
    for (int i = 0; i < 4; i++) {
      ah[i] = *(const bf16x8*)&Wh[(wn + 16 * i + fr) * LDK + fk];
      al[i] = *(const bf16x8*)&Wl[(wn + 16 * i + fr) * LDK + fk];
      bh[i] = *(const bf16x8*)&Xh[(wt + 16 * i + fr) * LDK + fk];
      bl[i] = *(const bf16x8*)&Xl[(wt + 16 * i + fr) * LDK + fk];
    }
#pragma unroll
    for (int i = 0; i < 4; i++)
#pragma unroll
      for (int j = 0; j < 4; j++) {
        acc[i][j] = __builtin_amdgcn_mfma_f32_16x16x32_bf16(ah[i], bh[j],
                                                            acc[i][j], 0, 0, 0);
        acc[i][j] = __builtin_amdgcn_mfma_f32_16x16x32_bf16(al[i], bh[j],
                                                            acc[i][j], 0, 0, 0);
        acc[i][j] = __builtin_amdgcn_mfma_f32_16x16x32_bf16(ah[i], bl[j],
                                                            acc[i][j], 0, 0, 0);
      }
  }
  const size_t obase = (size_t)b * 512 * 2048;
#pragma unroll
  for (int i = 0; i < 4; i++) {
#pragma unroll
    for (int r = 0; r < 4; r++) {
      int n = n0 + wn + 16 * i + (l >> 4) * 4 + r;
      float bsc = bias[n];
      size_t row = obase + (size_t)n * 2048 + t0 + wt + (l & 15);
#pragma unroll
      for (int j = 0; j < 4; j++) YT[row + 16 * j] = acc[i][j][r] + bsc;
    }
  }
}

// ---------------------------------------------------------------------------
// Plain-bf16 GEMM for v projection (pipelined, XCD-affine).
// ---------------------------------------------------------------------------
__global__ __launch_bounds__(256) void gemm_bf16_vproj(
    const float* __restrict__ X, const unsigned short* __restrict__ WThi,
    const float* __restrict__ bias, unsigned short* __restrict__ Vbf) {
  __shared__ __align__(16) unsigned short Ws[128 * LDK];
  __shared__ __align__(16) unsigned short Xs[128 * LDK];
  const int tid = threadIdx.x;
  int n0, b, t0;
  gemm_decode(blockIdx.x, n0, b, t0);
  const int w = tid >> 6, l = tid & 63;
  const int wr = (w & 1) * 64;
  const int wc = (w >> 1) * 64;
  const int fr = l & 15, fk = (l >> 4) * 8;

  f32x4 acc[4][4];
#pragma unroll
  for (int i = 0; i < 4; i++)
#pragma unroll
    for (int j = 0; j < 4; j++) acc[i][j] = (f32x4)0.f;

  const int srow = tid >> 1, scol = (tid & 1) * 16;
  const float* Xg = X + ((size_t)(b * 2048 + t0 + srow)) * 512 + scol;
  const unsigned short* Wg = WThi + ((size_t)(n0 + srow)) * 512 + scol;
  unsigned short* XsL = &Xs[srow * LDK + scol];
  unsigned short* WsL = &Ws[srow * LDK + scol];

  float xv[16];
  uint4 w0, w1;
  *(float4*)&xv[0] = *(const float4*)&Xg[0];
  *(float4*)&xv[4] = *(const float4*)&Xg[4];
  *(float4*)&xv[8] = *(const float4*)&Xg[8];
  *(float4*)&xv[12] = *(const float4*)&Xg[12];
  w0 = *(const uint4*)&Wg[0];
  w1 = *(const uint4*)&Wg[8];

  for (int k0 = 0; k0 < 512; k0 += 32) {
    union { unsigned short us[16]; uint4 q[2]; } hb;
#pragma unroll
    for (int i = 0; i < 16; i++) hb.us[i] = f2bf_rne(xv[i]);
    __syncthreads();
    *(uint4*)&XsL[0] = hb.q[0];
    *(uint4*)&XsL[8] = hb.q[1];
    *(uint4*)&WsL[0] = w0;
    *(uint4*)&WsL[8] = w1;
    __syncthreads();
    const int k1 = k0 + 32;
    if (k1 < 512) {
      *(float4*)&xv[0] = *(const float4*)&Xg[k1];
      *(float4*)&xv[4] = *(const float4*)&Xg[k1 + 4];
      *(float4*)&xv[8] = *(const float4*)&Xg[k1 + 8];
      *(float4*)&xv[12] = *(const float4*)&Xg[k1 + 12];
      w0 = *(const uint4*)&Wg[k1];
      w1 = *(const uint4*)&Wg[k1 + 8];
    }
    bf16x8 af[4], bf[4];
#pragma unroll
    for (int i = 0; i < 4; i++) {
      af[i] = *(const bf16x8*)&Xs[(wr + 16 * i + fr) * LDK + fk];
      bf[i] = *(const bf16x8*)&Ws[(wc + 16 * i + fr) * LDK + fk];
    }
#pragma unroll
    for (int i = 0; i < 4; i++)
#pragma unroll
      for (int j = 0; j < 4; j++)
        acc[i][j] = __builtin_amdgcn_mfma_f32_16x16x32_bf16(af[i], bf[j],
                                                            acc[i][j], 0, 0, 0);
  }
  float bj[4];
#pragma unroll
  for (int j = 0; j < 4; j++) bj[j] = bias[n0 + wc + 16 * j + (l & 15)];
#pragma unroll
  for (int i = 0; i < 4; i++) {
#pragma unroll
    for (int r = 0; r < 4; r++) {
      int t = t0 + wr + 16 * i + (l >> 4) * 4 + r;
      unsigned short* vrow = Vbf + ((size_t)(b * 2048 + t)) * 512;
#pragma unroll
      for (int j = 0; j < 4; j++) {
        int d = n0 + wc + 16 * j + (l & 15);
        vrow[d] = f2bf_rne(acc[i][j][r] + bj[j]);
      }
    }
  }
}

// ---------------------------------------------------------------------------
// Plain-bf16 GEMM for output projection (pipelined, XCD-affine).
// ---------------------------------------------------------------------------
__global__ __launch_bounds__(256) void gemm_bf16_out(
    const unsigned short* __restrict__ Abf,
    const unsigned short* __restrict__ WThi, const float* __restrict__ bias,
    float* __restrict__ Y) {
  __shared__ __align__(16) unsigned short Ws[128 * LDK];
  __shared__ __align__(16) unsigned short Xs[128 * LDK];
  const int tid = threadIdx.x;
  int n0, b, t0;
  gemm_decode(blockIdx.x, n0, b, t0);
  const int w = tid >> 6, l = tid & 63;
  const int wr = (w & 1) * 64;
  const int wc = (w >> 1) * 64;
  const int fr = l & 15, fk = (l >> 4) * 8;

  f32x4 acc[4][4];
#pragma unroll
  for (int i = 0; i < 4; i++)
#pragma unroll
    for (int j = 0; j < 4; j++) acc[i][j] = (f32x4)0.f;

  const int srow = tid >> 1, scol = (tid & 1) * 16;
  const unsigned short* Ag = Abf + ((size_t)(b * 2048 + t0 + srow)) * 512 + scol;
  const unsigned short* Wg = WThi + ((size_t)(n0 + srow)) * 512 + scol;
  unsigned short* XsL = &Xs[srow * LDK + scol];
  unsigned short* WsL = &Ws[srow * LDK + scol];

  uint4 a0, a1, w0, w1;
  a0 = *(const uint4*)&Ag[0];
  a1 = *(const uint4*)&Ag[8];
  w0 = *(const uint4*)&Wg[0];
  w1 = *(const uint4*)&Wg[8];

  for (int k0 = 0; k0 < 512; k0 += 32) {
    __syncthreads();
    *(uint4*)&XsL[0] = a0;
    *(uint4*)&XsL[8] = a1;
    *(uint4*)&WsL[0] = w0;
    *(uint4*)&WsL[8] = w1;
    __syncthreads();
    const int k1 = k0 + 32;
    if (k1 < 512) {
      a0 = *(const uint4*)&Ag[k1];
      a1 = *(const uint4*)&Ag[k1 + 8];
      w0 = *(const uint4*)&Wg[k1];
      w1 = *(const uint4*)&Wg[k1 + 8];
    }
    bf16x8 af[4], bf[4];
#pragma unroll
    for (int i = 0; i < 4; i++) {
      af[i] = *(const bf16x8*)&Xs[(wr + 16 * i + fr) * LDK + fk];
      bf[i] = *(const bf16x8*)&Ws[(wc + 16 * i + fr) * LDK + fk];
    }
#pragma unroll
    for (int i = 0; i < 4; i++)
#pragma unroll
      for (int j = 0; j < 4; j++)
        acc[i][j] = __builtin_amdgcn_mfma_f32_16x16x32_bf16(af[i], bf[j],
                                                            acc[i][j], 0, 0, 0);
  }
  float bj[4];
#pragma unroll
  for (int j = 0; j < 4; j++) bj[j] = bias[n0 + wc + 16 * j + (l & 15)];
#pragma unroll
  for (int i = 0; i < 4; i++) {
#pragma unroll
    for (int r = 0; r < 4; r++) {
      int t = t0 + wr + 16 * i + (l >> 4) * 4 + r;
      float* yrow = Y + ((size_t)(b * 2048 + t)) * 512;
#pragma unroll
      for (int j = 0; j < 4; j++) {
        int n = n0 + wc + 16 * j + (l & 15);
        yrow[n] = acc[i][j][r] + bj[j];
      }
    }
  }
}

// ---------------------------------------------------------------------------
// Radix-8 register FFT machinery (2048 = 8*8*8*4).
// ---------------------------------------------------------------------------
__device__ __forceinline__ float2 cadd(float2 a, float2 b) {
  return make_float2(a.x + b.x, a.y + b.y);
}
__device__ __forceinline__ float2 csub(float2 a, float2 b) {
  return make_float2(a.x - b.x, a.y - b.y);
}
__device__ __forceinline__ float2 cmulf(float2 a, float2 b) {
  return make_float2(a.x * b.x - a.y * b.y, a.x * b.y + a.y * b.x);
}
template <int SGN>  // -1 fwd (W = e^{-i...}), +1 inverse
__device__ __forceinline__ float2 mul_i(float2 a) {
  return (SGN < 0) ? make_float2(a.y, -a.x) : make_float2(-a.y, a.x);
}

template <int SGN>
__device__ __forceinline__ void dft4(float2 v[4]) {
  float2 b0 = cadd(v[0], v[2]);
  float2 b2 = csub(v[0], v[2]);
  float2 b1 = cadd(v[1], v[3]);
  float2 b3 = mul_i<SGN>(csub(v[1], v[3]));
  v[0] = cadd(b0, b1);
  v[2] = csub(b0, b1);
  v[1] = cadd(b2, b3);
  v[3] = csub(b2, b3);
}

template <int SGN>
__device__ __forceinline__ void dft8(float2 v[8]) {
  const float C = 0.70710678118654752f;
  float2 e[4], o[4];
#pragma unroll
  for (int i = 0; i < 4; i++) {
    e[i] = cadd(v[i], v[i + 4]);
    o[i] = csub(v[i], v[i + 4]);
  }
  {
    float s = o[1].x, t = o[1].y;
    o[1] = (SGN < 0) ? make_float2(C * (s + t), C * (t - s))
                     : make_float2(C * (s - t), C * (s + t));
  }
  o[2] = mul_i<SGN>(o[2]);
  {
    float s = o[3].x, t = o[3].y;
    o[3] = (SGN < 0) ? make_float2(C * (t - s), -C * (s + t))
                     : make_float2(-C * (s + t), C * (s - t));
  }
  dft4<SGN>(e);
  dft4<SGN>(o);
  v[0] = e[0]; v[2] = e[1]; v[4] = e[2]; v[6] = e[3];
  v[1] = o[0]; v[3] = o[1]; v[5] = o[2]; v[7] = o[3];
}

__device__ __forceinline__ void twiddle8_pair(float2 vz[8], float2 vw[8],
                                              float ang) {
  float2 T;
  __sincosf(ang, &T.y, &T.x);
  float2 t = T;
  vz[1] = cmulf(vz[1], t);
  vw[1] = cmulf(vw[1], t);
#pragma unroll
  for (int r = 2; r < 8; r++) {
    t = cmulf(t, T);
    vz[r] = cmulf(vz[r], t);
    vw[r] = cmulf(vw[r], t);
  }
}
__device__ __forceinline__ void twiddle8_one(float2 v[8], float ang) {
  float2 T;
  __sincosf(ang, &T.y, &T.x);
  float2 t = T;
  v[1] = cmulf(v[1], t);
#pragma unroll
  for (int r = 2; r < 8; r++) {
    t = cmulf(t, T);
    v[r] = cmulf(v[r], t);
  }
}

// ---------------------------------------------------------------------------
// FFT correlate: per (b, feature-pair) block. qT,kT: [B,512,2048] fp32.
// attn written IN PLACE over qT rows. Radix 8,8,8,4 DIF; natural-order
// spectrum obtained for free via rev3-digit quad assignment in stage 4.
// ---------------------------------------------------------------------------
__global__ __launch_bounds__(256) void fft_correlate(
    float* __restrict__ qT, const float* __restrict__ kT) {
  __shared__ float2 ldsZ[2112];
  __shared__ float2 ldsW[2112];
  const int b = blockIdx.x;
  const int d0 = blockIdx.y * 2;
  const int tid = threadIdx.x;
  const size_t base = ((size_t)b * 512 + d0) * 2048;

  const float W1 = -6.28318530717958647692f / 2048.f;
  const int j2 = tid & 31, j3 = tid & 3;
  const int s1 = tid >> 5, s2 = tid >> 2;
  const int f1 = ((tid & 7) << 6) | (tid & 56) | (tid >> 6);
  const int pt = tid + (tid >> 5);
  const int b2 = 264 * s1 + j2;
  const int b3 = 33 * s2 + j3;

  float2 vz[8], vw[8];
#pragma unroll
  for (int r = 0; r < 8; r++) {
    int t = tid + (r << 8);
    vz[r] = make_float2(qT[base + t], qT[base + 2048 + t]);
    vw[r] = make_float2(kT[base + t], kT[base + 2048 + t]);
  }

  dft8<-1>(vz);
  dft8<-1>(vw);
  twiddle8_pair(vz, vw, W1 * (float)tid);
#pragma unroll
  for (int r = 0; r < 8; r++) {
    ldsZ[pt + 264 * r] = vz[r];
    ldsW[pt + 264 * r] = vw[r];
  }
  __syncthreads();
#pragma unroll
  for (int m = 0; m < 8; m++) {
    vz[m] = ldsZ[b2 + 33 * m];
    vw[m] = ldsW[b2 + 33 * m];
  }
  dft8<-1>(vz);
  dft8<-1>(vw);
  twiddle8_pair(vz, vw, (W1 * 8.f) * (float)j2);
#pragma unroll
  for (int r = 0; r < 8; r++) {
    ldsZ[b2 + 33 * r] = vz[r];
    ldsW[b2 + 33 * r] = vw[r];
  }
  __syncthreads();
#pragma unroll
  for (int m = 0; m < 8; m++) {
    vz[m] = ldsZ[b3 + 4 * m];
    vw[m] = ldsW[b3 + 4 * m];
  }
  dft8<-1>(vz);
  dft8<-1>(vw);
  twiddle8_pair(vz, vw, (W1 * 64.f) * (float)j3);
#pragma unroll
  for (int r = 0; r < 8; r++) {
    ldsZ[b3 + 4 * r] = vz[r];
    ldsW[b3 + 4 * r] = vw[r];
  }
  __syncthreads();
  {
    float2 za[4], zb[4], wa[4], wb[4];
    const int pb = f1 << 2;
#pragma unroll
    for (int c = 0; c < 4; c++) {
      za[c] = ldsZ[FFT_PAD(pb + c)];
      zb[c] = ldsZ[FFT_PAD(pb + 16 + c)];
      wa[c] = ldsW[FFT_PAD(pb + c)];
      wb[c] = ldsW[FFT_PAD(pb + 16 + c)];
    }
    dft4<-1>(za);
    dft4<-1>(zb);
    dft4<-1>(wa);
    dft4<-1>(wb);
    __syncthreads();
#pragma unroll
    for (int c = 0; c < 4; c++) {
      ldsZ[pt + 528 * c] = za[c];
      ldsZ[pt + 264 + 528 * c] = zb[c];
      ldsW[pt + 528 * c] = wa[c];
      ldsW[pt + 264 + 528 * c] = wb[c];
    }
  }
  __syncthreads();

  float2 G[8];
#pragma unroll
  for (int r = 0; r < 8; r++) {
    int f = tid + (r << 8);
    int fn = (NFFT - f) & (NFFT - 1);
    float2 Zf = ldsZ[pt + 264 * r], Zn = ldsZ[FFT_PAD(fn)];
    float2 Wf = ldsW[pt + 264 * r], Wn = ldsW[FFT_PAD(fn)];
    float A1x = Zf.x + Zn.x, A1y = Zf.y - Zn.y;
    float B1x = Wf.x + Wn.x, B1y = Wn.y - Wf.y;
    float A2x = Zf.x - Zn.x, A2y = Zf.y + Zn.y;
    float B2x = Wf.x - Wn.x, B2y = -Wf.y - Wn.y;
    float p1x = A1x * B1x - A1y * B1y;
    float p1y = A1x * B1y + A1y * B1x;
    float p2x = A2x * B2x - A2y * B2y;
    float p2y = A2x * B2y + A2y * B2x;
    G[r] = make_float2(0.25f * (p1x - p2y), 0.25f * (p1y + p2x));
    (void)f;
  }
  __syncthreads();

  dft8<1>(G);
  twiddle8_one(G, (-W1) * (float)tid);
#pragma unroll
  for (int r = 0; r < 8; r++) ldsZ[pt + 264 * r] = G[r];
  __syncthreads();
#pragma unroll
  for (int m = 0; m < 8; m++) G[m] = ldsZ[b2 + 33 * m];
  dft8<1>(G);
  twiddle8_one(G, (-W1 * 8.f) * (float)j2);
#pragma unroll
  for (int r = 0; r < 8; r++) ldsZ[b2 + 33 * r] = G[r];
  __syncthreads();
#pragma unroll
  for (int m = 0; m < 8; m++) G[m] = ldsZ[b3 + 4 * m];
  dft8<1>(G);
  twiddle8_one(G, (-W1 * 64.f) * (float)j3);
#pragma unroll
  for (int r = 0; r < 8; r++) ldsZ[b3 + 4 * r] = G[r];
  __syncthreads();
  {
    float2 za[4], zb[4];
    const int pb = f1 << 2;
#pragma unroll
    for (int c = 0; c < 4; c++) {
      za[c] = ldsZ[FFT_PAD(pb + c)];
      zb[c] = ldsZ[FFT_PAD(pb + 16 + c)];
    }
    dft4<1>(za);
    dft4<1>(zb);
    const float scale = 1.0f / (float)NFFT;
#pragma unroll
    for (int c = 0; c < 4; c++) {
      int ta = tid + (c << 9);
      int tb = ta + 256;
      qT[base + ta] = za[c].x * scale;
      qT[base + 2048 + ta] = za[c].y * scale;
      qT[base + tb] = zb[c].x * scale;
      qT[base + 2048 + tb] = zb[c].y * scale;
    }
  }
}

// ---------------------------------------------------------------------------
// Column stats over d: mean (for top-k) + online softmax (max, expsum)
// ---------------------------------------------------------------------------
__global__ __launch_bounds__(256) void colstats_kernel(
    const float* __restrict__ attnT, float* __restrict__ mean,
    float2* __restrict__ stats) {
  const int b = blockIdx.x;
  const int t = blockIdx.y * 256 + threadIdx.x;
  const size_t base = (size_t)b * 512 * 2048 + t;
  float sum = 0.f, m = -1e30f, s = 0.f;
  for (int d = 0; d < 512; d++) {
    float a = attnT[base + (size_t)d * 2048];
    sum += a;
    float mn = fmaxf(m, a);
    s = s * __expf(m - mn) + __expf(a - mn);
    m = mn;
  }
  mean[b * 2048 + t] = sum * (1.f / 512.f);
  stats[b * 2048 + t] = make_float2(m, s);
}

// ---------------------------------------------------------------------------
// Top-15 per batch (iterative argmax, lowest-index tie-break)
// ---------------------------------------------------------------------------
__global__ __launch_bounds__(256) void topk_kernel(
    const float* __restrict__ mean, int* __restrict__ delays) {
  __shared__ float vals[2048];
  __shared__ float sv[256];
  __shared__ int si[256];
  const int b = blockIdx.x, tid = threadIdx.x;
#pragma unroll
  for (int r = 0; r < 8; r++)
    vals[tid + (r << 8)] = mean[b * 2048 + tid + (r << 8)];
  __syncthreads();
  for (int k = 0; k < 15; k++) {
    float bv = -1e30f;
    int bi = 1 << 30;
#pragma unroll
    for (int r = 0; r < 8; r++) {
      int i = (r << 8) + tid;
      float v = vals[i];
      if (v > bv || (v == bv && i < bi)) { bv = v; bi = i; }
    }
    sv[tid] = bv;
    si[tid] = bi;
    __syncthreads();
    for (int off = 128; off > 0; off >>= 1) {
      if (tid < off) {
        float v2 = sv[tid + off];
        int i2 = si[tid + off];
        if (v2 > sv[tid] || (v2 == sv[tid] && i2 < si[tid])) {
          sv[tid] = v2;
          si[tid] = i2;
        }
      }
      __syncthreads();
    }
    if (tid == 0) {
      delays[b * 15 + k] = si[0];
      vals[si[0]] = -1e30f;
    }
    __syncthreads();
  }
}

// ---------------------------------------------------------------------------
// Context: ctx[b][t][d] = softmax_d(attn)[d][t] * sum_k v[b][(t-dly_k)%T][d]
// Tiled: block = (b, 64-t tile); d in 64-wide chunks. attn staged through a
// padded LDS tile (coalesced along t); v read as 2x uint4 per delay; XCD-
// affine swizzle keeps all tiles of one b on one XCD (v L2 residency).
// ---------------------------------------------------------------------------
__global__ __launch_bounds__(256) void ctx_kernel(
    const float* __restrict__ attnT, const unsigned short* __restrict__ vbf,
    const float2* __restrict__ stats, const int* __restrict__ delays,
    unsigned short* __restrict__ ctx) {
  __shared__ float atile[64][65];
  __shared__ int dly[15];
  const int lin = blockIdx.x;
  const int g = lin >> 8;              // b-group of 8
  const int r = lin & 255;
  const int b = g * 8 + (r & 7);       // XCD = lin % 8 = b % 8
  const int tb = (r >> 3) * 64;        // t-tile base
  const int tid = threadIdx.x;
  if (tid < 15) dly[tid] = delays[b * 15 + tid];
  __syncthreads();

  const int tl = tid >> 2;             // local t / load row (0..63)
  const int dq = (tid & 3) * 16;       // d-sub base within 64-chunk
  const int tq = (tid & 3) * 4;        // t-sub base for load phase
  const int t = tb + tl;
  const float2 st = stats[b * 2048 + t];
  const float m = st.x, inv_s = 1.f / st.y;

  int rowoff[15];
#pragma unroll
  for (int k = 0; k < 15; k++)
    rowoff[k] = ((t - dly[k]) & 2047) * 512;

  const size_t vbase = (size_t)b * 2048 * 512;
  const size_t abase = (size_t)b * 512 * 2048;

  for (int d0 = 0; d0 < 512; d0 += 64) {
    __syncthreads();  // previous chunk's atile reads complete
#pragma unroll
    for (int tt = 0; tt < 4; tt++) {
      float4 a4 = *(const float4*)&attnT[abase + (size_t)(d0 + tl) * 2048 +
                                         tb + tt * 16 + tq];
      atile[tt * 16 + tq + 0][tl] = a4.x;
      atile[tt * 16 + tq + 1][tl] = a4.y;
      atile[tt * 16 + tq + 2][tl] = a4.z;
      atile[tt * 16 + tq + 3][tl] = a4.w;
    }
    __syncthreads();

    float rolled[16];
#pragma unroll
    for (int i = 0; i < 16; i++) rolled[i] = 0.f;
#pragma unroll
    for (int k = 0; k < 15; k++) {
      const uint4* vp = (const uint4*)(vbf + vbase + rowoff[k] + d0 + dq);
      uint4 v0 = vp[0], v1 = vp[1];
      unsigned uu[8] = {v0.x, v0.y, v0.z, v0.w, v1.x, v1.y, v1.z, v1.w};
#pragma unroll
      for (int w = 0; w < 8; w++) {
        rolled[2 * w + 0] += __uint_as_float(uu[w] << 16);
        rolled[2 * w + 1] += __uint_as_float(uu[w] & 0xffff0000u);
      }
    }

    union { unsigned short us[16]; uint4 q[2]; } ob;
#pragma unroll
    for (int i = 0; i < 16; i++) {
      float a = atile[tl][dq + i];
      float p = __expf(a - m) * inv_s;
      ob.us[i] = f2bf_rne(p * rolled[i]);
    }
    uint4* op = (uint4*)(ctx + vbase + (size_t)t * 512 + d0 + dq);
    op[0] = ob.q[0];
    op[1] = ob.q[1];
  }
}

// ---------------------------------------------------------------------------
extern "C" void kernel_launch(void* const* d_in, const int* in_sizes, int n_in,
                              void* d_out, int out_size, void* d_ws,
                              size_t ws_size, hipStream_t stream) {
  const float* query = (const float*)d_in[0];
  const float* key_in = (const float*)d_in[1];
  const float* value = (const float*)d_in[2];
  const float* Wq = (const float*)d_in[3];
  const float* bq = (const float*)d_in[4];
  const float* Wk = (const float*)d_in[5];
  const float* bk = (const float*)d_in[6];
  const float* Wv = (const float*)d_in[7];
  const float* bv = (const float*)d_in[8];
  const float* Wo = (const float*)d_in[9];
  const float* bo = (const float*)d_in[10];
  float* out = (float*)d_out;

  float* ws = (float*)d_ws;
  const size_t SZ = (size_t)32 * 512 * 2048;  // floats per [B,512,2048] tensor
  float* qT = ws;          // fp32 q -> attn (in place)
  float* kT = ws + SZ;     // fp32 k; REUSED after fft: vbf (first half) + ctx
  unsigned short* vbf = (unsigned short*)(ws + SZ);
  unsigned short* ctxbf = (unsigned short*)(ws + SZ + SZ / 2);
  unsigned short* wbuf = (unsigned short*)(ws + 2 * SZ);  // 2,097,152 ushorts
  float* mean = ws + 2 * SZ + 1048576;                    // 65536
  float2* stats = (float2*)(ws + 2 * SZ + 1048576 + 65536);  // 65536 float2
  int* delays = (int*)(ws + 2 * SZ + 1048576 + 65536 + 131072);

  const unsigned short* wq_hi = wbuf + 0 * 524288;
  const unsigned short* wq_lo = wq_hi + 262144;
  const unsigned short* wk_hi = wbuf + 1 * 524288;
  const unsigned short* wk_lo = wk_hi + 262144;
  const unsigned short* wv_hi = wbuf + 2 * 524288;
  const unsigned short* wo_hi = wbuf + 3 * 524288;

  wsplit_kernel<<<dim3(16, 16, 4), 256, 0, stream>>>(Wq, Wk, Wv, Wo, wbuf);

  proj_gemm_split<<<2048, 256, 0, stream>>>(query, wq_hi, wq_lo, bq, qT);
  proj_gemm_split<<<2048, 256, 0, stream>>>(key_in, wk_hi, wk_lo, bk, kT);

  fft_correlate<<<dim3(32, 256), 256, 0, stream>>>(qT, kT);

  // v projection AFTER fft (vbf aliases kT region)
  gemm_bf16_vproj<<<2048, 256, 0, stream>>>(value, wv_hi, bv, vbf);

  colstats_kernel<<<dim3(32, 8), 256, 0, stream>>>(qT, mean, stats);
  topk_kernel<<<32, 256, 0, stream>>>(mean, delays);
  ctx_kernel<<<1024, 256, 0, stream>>>(qT, vbf, stats, delays, ctxbf);

  gemm_bf16_out<<<2048, 256, 0, stream>>>(ctxbf, wo_hi, bo, out);
}